// Round 18
// baseline (130.913 us; speedup 1.0000x reference)
//
#include <hip/hip_runtime.h>
#include <hip/hip_bf16.h>
#include <cstdint>
#include <cstddef>

typedef unsigned short u16;
typedef unsigned int   u32;
typedef __attribute__((ext_vector_type(8))) short short8;
typedef __attribute__((ext_vector_type(4))) short short4v;
typedef __attribute__((ext_vector_type(4))) float f32x4;

#define D_MODEL 1024
#define NH      16
#define HD      64
#define SEQ     2048
#define BATCH   2
#define MTOT    (BATCH*SEQ)   // 4096
#define NQKV    3072
#define VTS     2056          // padded V^T row stride (elems)

__device__ __forceinline__ float bf2f(u16 h){ u32 u = ((u32)h) << 16; float f; __builtin_memcpy(&f, &u, 4); return f; }
__device__ __forceinline__ u16 f2bf(float f){ u32 u; __builtin_memcpy(&u, &f, 4); u = (u + 0x7FFFu + ((u >> 16) & 1u)) >> 16; return (u16)u; }

// packed fp32->bf16 via the official HIP intrinsic (RNE; R14-proven).
__device__ __forceinline__ u32 pkbf(float a, float b){
  __hip_bfloat162 h = __float22bfloat162_rn(make_float2(a, b));
  u32 r; __builtin_memcpy(&r, &h, 4); return r;
}
__device__ __forceinline__ short4v pack4(float a, float b, float c, float d){
  u32 lo = pkbf(a, b), hi = pkbf(c, d);
  short4v r;
  __builtin_memcpy(&r, &lo, 4);
  __builtin_memcpy(((char*)&r) + 4, &hi, 4);
  return r;
}

__device__ __forceinline__ void gload16(const void* g, void* s){
  __builtin_amdgcn_global_load_lds((const __attribute__((address_space(1))) void*)g,
                                   (__attribute__((address_space(3))) void*)s, 16, 0, 0);
}

// ------- convert fp32 -> bf16 (x, Wq|Wk|Wv packed, Wo) + RoPE table (fused) -----
__global__ __launch_bounds__(256) void convert_kernel(
    const float4* __restrict__ x, const float4* __restrict__ wq, const float4* __restrict__ wk,
    const float4* __restrict__ wv, const float4* __restrict__ wo,
    u16* __restrict__ xb, u16* __restrict__ wqkvb, u16* __restrict__ wob,
    float2* __restrict__ tab)
{
  int bid = blockIdx.x;
  if (bid >= 8192) {                                // RoPE cos/sin table part
    int i = (bid - 8192) * 256 + threadIdx.x;       // 65536 = 2048 pos * 32 pairs
    int pos = i >> 5, p = i & 31;
    float freq = __expf(-(float)p * (9.210340371976184f / 32.0f));
    float ang = (float)pos * freq;
    float s, c;
    sincosf(ang, &s, &c);
    tab[i] = make_float2(c, s);
    return;
  }
  int i = bid * 256 + threadIdx.x;                  // 2,097,152 units of 4 floats
  const float4* src; u16* dst;
  if (i < 1048576) {                                // x
    src = x + i; dst = xb + (size_t)i * 4;
  } else if (i < 1835008) {                         // Wq,Wk,Wv
    int j = i - 1048576;
    int w = j >> 18;
    int e = j & 262143;
    src = (w == 0 ? wq : (w == 1 ? wk : wv)) + e;
    dst = wqkvb + (size_t)w * 1048576 + (size_t)e * 4;
  } else {                                          // Wo
    int j = i - 1835008;
    src = wo + j; dst = wob + (size_t)j * 4;
  }
  float4 v = *src;
  u32 lo = (u32)f2bf(v.x) | ((u32)f2bf(v.y) << 16);
  u32 hi = (u32)f2bf(v.z) | ((u32)f2bf(v.w) << 16);
  u32* d32 = (u32*)dst;
  d32[0] = lo; d32[1] = hi;
}

// ------- fused prep: RoPE apply on Q,K columns  +  V transpose (disjoint data) --
__global__ __launch_bounds__(256) void prep_kernel(
    u16* __restrict__ qkv, const int* __restrict__ tpos, const float2* __restrict__ tab,
    u16* __restrict__ vt)
{
  int bid = blockIdx.x;
  if (bid < 16384) {
    int tid = bid * 256 + threadIdx.x;              // 4096 rows * 1024 pairs
    int m    = tid >> 10;
    int pp   = tid & 1023;
    int slot = pp >> 5;
    int p    = pp & 31;
    int col  = slot * 64 + 2 * p;
    u32* addr = (u32*)(qkv + (size_t)m * NQKV + col);
    u32 v = *addr;
    float x1 = bf2f((u16)(v & 0xffff));
    float x2 = bf2f((u16)(v >> 16));
    int pos = tpos[m];
    float2 cs = tab[(size_t)pos * 32 + p];
    float r1 = x1 * cs.x - x2 * cs.y;
    float r2 = x1 * cs.y + x2 * cs.x;
    *addr = (u32)f2bf(r1) | ((u32)f2bf(r2) << 16);
  } else {
    int idx  = bid - 16384;                         // 0..2047
    int kblk = idx & 7;
    int d0   = (idx >> 3) & 7;
    int bh   = idx >> 6;
    int b = bh >> 4, h = bh & 15;
    int k = kblk * 256 + threadIdx.x;
    const u16* src = qkv + (size_t)(b * SEQ + k) * NQKV + 2 * D_MODEL + h * HD + d0 * 8;
    short8 v = *(const short8*)src;
    u16* dst = vt + ((size_t)bh * HD + d0 * 8) * VTS + k;
    #pragma unroll
    for (int j = 0; j < 8; ++j) dst[(size_t)j * VTS] = (u16)v[j];
  }
}

// ---------------- bf16 GEMM, C[m][n] = sum_k A[m][k]*B[n][k]  (B^T layout) ------
// 128x128 tile, 3-slot ring, single barrier (R16-proven), XCD swizzle (T1).
template<typename OutT>
__global__ __launch_bounds__(256) void gemm_bt(
    const u16* __restrict__ A, const u16* __restrict__ B, OutT* __restrict__ C,
    int M, int N, int K, int NBX)
{
  __shared__ __align__(16) u16 As[3][128 * 32];   // 24 KB
  __shared__ __align__(16) u16 Bs[3][128 * 32];   // 24 KB
  int lin = blockIdx.x;
  int per = (int)gridDim.x >> 3;
  int swz = (lin & 7) * per + (lin >> 3);          // bijective (gridDim.x % 8 == 0)
  int bx = swz % NBX, by = swz / NBX;
  int t = threadIdx.x;
  int w = t >> 6, l = t & 63, g = l >> 4, c = l & 15;
  int wr = w >> 1, wc = w & 1;
  int bm = by * 128, bn = bx * 128;

  const u16* aS0 = A + (size_t)(bm + (t >> 2)) * K + (t & 3) * 8;
  const u16* aS1 = aS0 + (size_t)64 * K;
  const u16* bS0 = B + (size_t)(bn + (t >> 2)) * K + (t & 3) * 8;
  const u16* bS1 = bS0 + (size_t)64 * K;

  auto STAGE = [&](int step) {
    int slot = step % 3;
    int kk = step * 32;
    gload16(aS0 + kk, (char*)&As[slot][0] + w * 1024);
    gload16(aS1 + kk, (char*)&As[slot][0] + 4096 + w * 1024);
    gload16(bS0 + kk, (char*)&Bs[slot][0] + w * 1024);
    gload16(bS1 + kk, (char*)&Bs[slot][0] + 4096 + w * 1024);
  };

  f32x4 z = {0.f, 0.f, 0.f, 0.f};
  f32x4 acc[4][4];
  #pragma unroll
  for (int i = 0; i < 4; i++)
    #pragma unroll
    for (int j = 0; j < 4; j++) acc[i][j] = z;

  int nk = K >> 5;
  STAGE(0);
  if (nk > 1) STAGE(1);

  for (int step = 0; step < nk; ++step) {
    if (step + 1 < nk) {
      asm volatile("s_waitcnt vmcnt(4)" ::: "memory");   // only next tile's 4 in flight
    } else {
      asm volatile("s_waitcnt vmcnt(0)" ::: "memory");
    }
    __syncthreads();
    if (step + 2 < nk) STAGE(step + 2);                  // overwrites slot (step-1)%3: safe

    int slot = step % 3;
    const u16* Ac = &As[slot][0];
    const u16* Bc = &Bs[slot][0];
    short8 af[4], bfr[4];
    #pragma unroll
    for (int i = 0; i < 4; i++)
      af[i] = *(const short8*)&Ac[(size_t)(wr * 64 + i * 16 + c) * 32 + g * 8];
    #pragma unroll
    for (int j = 0; j < 4; j++)
      bfr[j] = *(const short8*)&Bc[(size_t)(wc * 64 + j * 16 + c) * 32 + g * 8];
    #pragma unroll
    for (int i = 0; i < 4; i++)
      #pragma unroll
      for (int j = 0; j < 4; j++)
        acc[i][j] = __builtin_amdgcn_mfma_f32_16x16x32_bf16(af[i], bfr[j], acc[i][j], 0, 0, 0);
  }

  #pragma unroll
  for (int i = 0; i < 4; i++) {
    int row0 = bm + wr * 64 + i * 16 + 4 * g;
    #pragma unroll
    for (int j = 0; j < 4; j++) {
      int col = bn + wc * 64 + j * 16 + c;
      #pragma unroll
      for (int r = 0; r < 4; r++) {
        float v = acc[i][j][r];
        size_t idx = (size_t)(row0 + r) * N + col;
        if constexpr (sizeof(OutT) == 2) ((u16*)C)[idx] = f2bf(v);
        else                             ((float*)C)[idx] = v;
      }
    }
  }
}

// ---------------- bf16 GEMM small-N: 128x64 tile, same single-barrier ring ------
__global__ __launch_bounds__(256) void gemm_bt_small(
    const u16* __restrict__ A, const u16* __restrict__ B, float* __restrict__ C,
    int M, int N, int K, int NBX)
{
  __shared__ __align__(16) u16 As[3][128 * 32];   // 24 KB
  __shared__ __align__(16) u16 Bs[3][64 * 32];    // 12 KB
  int lin = blockIdx.x;
  int per = (int)gridDim.x >> 3;
  int swz = (lin & 7) * per + (lin >> 3);
  int bx = swz % NBX, by = swz / NBX;
  int t = threadIdx.x;
  int w = t >> 6, l = t & 63, g = l >> 4, c = l & 15;
  int wr = w >> 1, wc = w & 1;
  int bm = by * 128, bn = bx * 64;

  const u16* aS0 = A + (size_t)(bm + (t >> 2)) * K + (t & 3) * 8;
  const u16* aS1 = aS0 + (size_t)64 * K;
  const u16* bS0 = B + (size_t)(bn + (t >> 2)) * K + (t & 3) * 8;

  auto STAGE = [&](int step) {
    int slot = step % 3;
    int kk = step * 32;
    gload16(aS0 + kk, (char*)&As[slot][0] + w * 1024);
    gload16(aS1 + kk, (char*)&As[slot][0] + 4096 + w * 1024);
    gload16(bS0 + kk, (char*)&Bs[slot][0] + w * 1024);
  };

  f32x4 z = {0.f, 0.f, 0.f, 0.f};
  f32x4 acc[4][2];
  #pragma unroll
  for (int i = 0; i < 4; i++) { acc[i][0] = z; acc[i][1] = z; }

  int nk = K >> 5;
  STAGE(0);
  if (nk > 1) STAGE(1);

  for (int step = 0; step < nk; ++step) {
    if (step + 1 < nk) {
      asm volatile("s_waitcnt vmcnt(3)" ::: "memory");
    } else {
      asm volatile("s_waitcnt vmcnt(0)" ::: "memory");
    }
    __syncthreads();
    if (step + 2 < nk) STAGE(step + 2);

    int slot = step % 3;
    const u16* Ac = &As[slot][0];
    const u16* Bc = &Bs[slot][0];
    short8 af[4], bfr[2];
    #pragma unroll
    for (int i = 0; i < 4; i++)
      af[i] = *(const short8*)&Ac[(size_t)(wr * 64 + i * 16 + c) * 32 + g * 8];
    #pragma unroll
    for (int j = 0; j < 2; j++)
      bfr[j] = *(const short8*)&Bc[(size_t)(wc * 32 + j * 16 + c) * 32 + g * 8];
    #pragma unroll
    for (int i = 0; i < 4; i++)
      #pragma unroll
      for (int j = 0; j < 2; j++)
        acc[i][j] = __builtin_amdgcn_mfma_f32_16x16x32_bf16(af[i], bfr[j], acc[i][j], 0, 0, 0);
  }

  #pragma unroll
  for (int i = 0; i < 4; i++) {
    int row0 = bm + wr * 64 + i * 16 + 4 * g;
    #pragma unroll
    for (int j = 0; j < 2; j++) {
      int col = bn + wc * 32 + j * 16 + c;
      #pragma unroll
      for (int r = 0; r < 4; r++)
        C[(size_t)(row0 + r) * N + col] = acc[i][j][r];
    }
  }
}

// ---------------- causal flash attention ----------------------------------------
// R17: 2-slot ring (32 KB LDS) -> 5-blocks/CU capacity; all 1024 blocks
// resident, 16 waves/CU (vs 12). Depth-1 prefetch, single barrier, vmcnt(0).
// Balanced qblk map: per-CU block sets (stride-256) sum to 66 tiles exactly.
// Numerics byte-identical to R14-16 (raw-max exp2 softmax, exact skip-rescale,
// packed RNE converts). bh = lin&31 keeps XCD L2 affinity.
#define STAGE_TILE(ktile)                                                       \
  {                                                                             \
    int _slot = (ktile) & 1;                                                    \
    int _k0 = (ktile) << 6;                                                     \
    _Pragma("unroll")                                                           \
    for (int _i = 0; _i < 2; ++_i) {                                            \
      int _row = w * 16 + _i * 8 + srow8;                                       \
      gload16(Kb + (size_t)(_k0 + _row) * NQKV + swzc,                          \
              (char*)&Ks[_slot][0] + w * 2048 + _i * 1024);                     \
      gload16(Vtb + (size_t)_row * VTS + _k0 + swzc,                            \
              (char*)&Vs[_slot][0] + w * 2048 + _i * 1024);                     \
    }                                                                           \
  }

__global__ __launch_bounds__(256) void attn_kernel(
    const u16* __restrict__ qkv, const u16* __restrict__ vt, u16* __restrict__ ctx)
{
  __shared__ __align__(16) u16 Ks[2][64 * 64];   // 16 KB
  __shared__ __align__(16) u16 Vs[2][64 * 64];   // 16 KB
  const float C1 = 0.18033688011112042f;         // 0.125 * log2(e)
  int lin  = blockIdx.x;                         // 0..1023
  int bh   = lin & 31;                           // stable bh->XCD affinity
  // balanced qblk map: v=lin>>5, j=v>>3, a=v&7; any {a, a+8, a+16, a+24} set
  // (stride-256 blocks, typical same-CU assignment) sums to 62 (+4 = 66 tiles).
  int v_ = lin >> 5, j_ = v_ >> 3, a_ = v_ & 7;
  int qblk = (j_ == 0) ? (31 - a_) : (j_ == 1) ? (16 + a_) : (j_ == 2) ? (15 - a_) : a_;
  int b = bh >> 4, h = bh & 15;
  int t = threadIdx.x;
  int w = t >> 6, l = t & 63, g = l >> 4, c = l & 15;
  const u16* base = qkv + (size_t)b * SEQ * NQKV;
  const u16* Qb = base + h * HD;
  const u16* Kb = base + D_MODEL + h * HD;
  const u16* Vtb = vt + (size_t)bh * HD * VTS;   // [d][k], row stride VTS

  int srow8 = l >> 3;                 // 0..7 row within issue
  int swzc  = ((l & 7) ^ srow8) << 3; // inverse-swizzled chunk -> elem offset

  f32x4 z = {0.f, 0.f, 0.f, 0.f};
  int q0 = qblk * 64 + w * 16;
  int q = q0 + c;
  short8 qf0 = *(const short8*)(Qb + (size_t)q * NQKV + g * 8);
  short8 qf1 = *(const short8*)(Qb + (size_t)q * NQKV + 32 + g * 8);

  f32x4 o[4] = {z, z, z, z};
  float mrun = -1e30f, lrun = 0.f;

  // ---- prologue: stage tile 0 ----
  STAGE_TILE(0);

  for (int kt = 0; kt <= qblk; ++kt) {
    int k0 = kt << 6;
    asm volatile("s_waitcnt vmcnt(0)" ::: "memory");     // tile kt's loads done
    __syncthreads();
    if (kt + 1 <= qblk) STAGE_TILE(kt + 1);              // slot (kt+1)&1: its readers
                                                         // finished before this barrier
    int slot = kt & 1;
    const u16* Kc = &Ks[slot][0];
    const u16* Vc = &Vs[slot][0];

    // ---- QK^T: S^T[k][q] (raw scores), 4 sub-tiles of 16 keys ----
    f32x4 s[4] = {z, z, z, z};
    #pragma unroll
    for (int sub = 0; sub < 4; ++sub) {
      const u16* kr = Kc + (sub * 16 + c) * 64;
      short8 kf0 = *(const short8*)(kr + ((g       ^ (c & 7)) << 3));
      short8 kf1 = *(const short8*)(kr + (((4 + g) ^ (c & 7)) << 3));
      s[sub] = __builtin_amdgcn_mfma_f32_16x16x32_bf16(kf0, qf0, s[sub], 0, 0, 0);
      s[sub] = __builtin_amdgcn_mfma_f32_16x16x32_bf16(kf1, qf1, s[sub], 0, 0, 0);
    }

    // ---- causal mask (raw domain, only last tile) ----
    float sc[4][4];
    if (kt == qblk) {
      #pragma unroll
      for (int sub = 0; sub < 4; ++sub)
        #pragma unroll
        for (int r = 0; r < 4; ++r) {
          int k = k0 + sub * 16 + 4 * g + r;
          sc[sub][r] = (k <= q) ? s[sub][r] : -1e30f;
        }
    } else {
      #pragma unroll
      for (int sub = 0; sub < 4; ++sub)
        #pragma unroll
        for (int r = 0; r < 4; ++r)
          sc[sub][r] = s[sub][r];
    }

    // ---- online softmax (raw max; exp2 folded scale; exact skip-rescale) ----
    float tm = fmaxf(fmaxf(fmaxf(sc[0][0], sc[0][1]), fmaxf(sc[0][2], sc[0][3])),
                     fmaxf(fmaxf(sc[1][0], sc[1][1]), fmaxf(sc[1][2], sc[1][3])));
    float tm2 = fmaxf(fmaxf(fmaxf(sc[2][0], sc[2][1]), fmaxf(sc[2][2], sc[2][3])),
                      fmaxf(fmaxf(sc[3][0], sc[3][1]), fmaxf(sc[3][2], sc[3][3])));
    tm = fmaxf(tm, tm2);
    tm = fmaxf(tm, __shfl_xor(tm, 16));
    tm = fmaxf(tm, __shfl_xor(tm, 32));
    // If no lane's max grew, alpha == 1 exactly -> rescale is the identity.
    if (!__all(tm <= mrun)) {
      float mnew = fmaxf(mrun, tm);
      float alpha = __builtin_amdgcn_exp2f((mrun - mnew) * C1);
      lrun *= alpha;
      #pragma unroll
      for (int dt = 0; dt < 4; ++dt) {
        o[dt][0] *= alpha; o[dt][1] *= alpha; o[dt][2] *= alpha; o[dt][3] *= alpha;
      }
      mrun = mnew;
    }
    float nb = -mrun * C1;
    float rs = 0.f;
    #pragma unroll
    for (int sub = 0; sub < 4; ++sub) {
      #pragma unroll
      for (int r = 0; r < 4; ++r) {
        sc[sub][r] = __builtin_amdgcn_exp2f(fmaf(sc[sub][r], C1, nb));
        rs += sc[sub][r];
      }
    }
    rs += __shfl_xor(rs, 16);
    rs += __shfl_xor(rs, 32);
    lrun += rs;

    // ---- P -> bf16 fragments (packed RNE convert, R14-proven) ----
    short4v pf[4];
    #pragma unroll
    for (int sub = 0; sub < 4; ++sub)
      pf[sub] = pack4(sc[sub][0], sc[sub][1], sc[sub][2], sc[sub][3]);

    // ---- PV: O^T[d][q] += V^T[d][k] * P^T[k][q], swizzled b64 LDS reads ----
    #pragma unroll
    for (int sub = 0; sub < 4; ++sub) {
      #pragma unroll
      for (int dt = 0; dt < 4; ++dt) {
        int ch = sub * 2 + (g >> 1);
        const u16* vp = Vc + (dt * 16 + c) * 64 + ((ch ^ (c & 7)) << 3) + ((g & 1) << 2);
        short4v vf = *(const short4v*)vp;
        o[dt] = __builtin_amdgcn_mfma_f32_16x16x16bf16_1k(vf, pf[sub], o[dt], 0, 0, 0);
      }
    }
    // no trailing barrier: next iter's pre-compute barrier orders slot reuse
  }

  float inv = 1.0f / lrun;
  size_t obase = ((size_t)b * SEQ + q) * D_MODEL + h * HD;
  #pragma unroll
  for (int dt = 0; dt < 4; ++dt) {
    u32 lo = pkbf(o[dt][0] * inv, o[dt][1] * inv);
    u32 hi = pkbf(o[dt][2] * inv, o[dt][3] * inv);
    u32* dp = (u32*)(ctx + obase + dt * 16 + 4 * g);
    dp[0] = lo; dp[1] = hi;
  }
}

// ---------------- launch ----------------
extern "C" void kernel_launch(void* const* d_in, const int* in_sizes, int n_in,
                              void* d_out, int out_size, void* d_ws, size_t ws_size,
                              hipStream_t stream)
{
  const float* x   = (const float*)d_in[0];
  const int*  tpos = (const int*) d_in[1];
  const float* Wq  = (const float*)d_in[2];
  const float* Wk  = (const float*)d_in[3];
  const float* Wv  = (const float*)d_in[4];
  const float* Wo  = (const float*)d_in[5];

  char* ws = (char*)d_ws;
  u16*    xb    = (u16*)(ws);                   //  8,388,608 B (dead after gemm1)
  u16*    vt    = (u16*)(ws);                   //  8,421,376 B V^T (clobbers dead xb)
  u16*    wqkvb = (u16*)(ws + 8388608);         //  6,291,456 B (dead after gemm1)
  u16*    wob   = (u16*)(ws + 14680064);        //  2,097,152 B
  u16*    qkvb  = (u16*)(ws + 16777216);        // 25,165,824 B
  u16*    ctx   = (u16*)(ws + 41943040);        //  8,388,608 B
  float2* tab   = (float2*)(ws + 50331648);     //    524,288 B

  convert_kernel<<<8448, 256, 0, stream>>>(
      (const float4*)x, (const float4*)Wq, (const float4*)Wk, (const float4*)Wv, (const float4*)Wo,
      xb, wqkvb, wob, tab);
  gemm_bt<u16><<<(NQKV / 128) * (MTOT / 128), 256, 0, stream>>>(
      xb, wqkvb, qkvb, MTOT, NQKV, D_MODEL, NQKV / 128);
  prep_kernel<<<18432, 256, 0, stream>>>(qkvb, tpos, tab, vt);
  attn_kernel<<<1024, 256, 0, stream>>>(qkvb, vt, ctx);
  gemm_bt_small<<<(D_MODEL / 64) * (MTOT / 128), 256, 0, stream>>>(
      ctx, wob, (float*)d_out, MTOT, D_MODEL, D_MODEL, D_MODEL / 64);
}

// Round 19
// 125.745 us; speedup vs baseline: 1.0411x; 1.0411x over previous
//
#include <hip/hip_runtime.h>
#include <hip/hip_bf16.h>
#include <cstdint>
#include <cstddef>

typedef unsigned short u16;
typedef unsigned int   u32;
typedef __attribute__((ext_vector_type(8))) short short8;
typedef __attribute__((ext_vector_type(4))) short short4v;
typedef __attribute__((ext_vector_type(4))) float f32x4;

#define D_MODEL 1024
#define NH      16
#define HD      64
#define SEQ     2048
#define BATCH   2
#define MTOT    (BATCH*SEQ)   // 4096
#define NQKV    3072
#define VTS     2056          // padded V^T row stride (elems)

__device__ __forceinline__ float bf2f(u16 h){ u32 u = ((u32)h) << 16; float f; __builtin_memcpy(&f, &u, 4); return f; }
__device__ __forceinline__ u16 f2bf(float f){ u32 u; __builtin_memcpy(&u, &f, 4); u = (u + 0x7FFFu + ((u >> 16) & 1u)) >> 16; return (u16)u; }

// packed fp32->bf16 via the official HIP intrinsic (RNE; R14-proven).
__device__ __forceinline__ u32 pkbf(float a, float b){
  __hip_bfloat162 h = __float22bfloat162_rn(make_float2(a, b));
  u32 r; __builtin_memcpy(&r, &h, 4); return r;
}
__device__ __forceinline__ short4v pack4(float a, float b, float c, float d){
  u32 lo = pkbf(a, b), hi = pkbf(c, d);
  short4v r;
  __builtin_memcpy(&r, &lo, 4);
  __builtin_memcpy(((char*)&r) + 4, &hi, 4);
  return r;
}

__device__ __forceinline__ void gload16(const void* g, void* s){
  __builtin_amdgcn_global_load_lds((const __attribute__((address_space(1))) void*)g,
                                   (__attribute__((address_space(3))) void*)s, 16, 0, 0);
}

// ------- convert fp32 -> bf16 (x, Wq|Wk|Wv packed, Wo) + RoPE table (fused) -----
__global__ __launch_bounds__(256) void convert_kernel(
    const float4* __restrict__ x, const float4* __restrict__ wq, const float4* __restrict__ wk,
    const float4* __restrict__ wv, const float4* __restrict__ wo,
    u16* __restrict__ xb, u16* __restrict__ wqkvb, u16* __restrict__ wob,
    float2* __restrict__ tab)
{
  int bid = blockIdx.x;
  if (bid >= 8192) {                                // RoPE cos/sin table part
    int i = (bid - 8192) * 256 + threadIdx.x;       // 65536 = 2048 pos * 32 pairs
    int pos = i >> 5, p = i & 31;
    float freq = __expf(-(float)p * (9.210340371976184f / 32.0f));
    float ang = (float)pos * freq;
    float s, c;
    sincosf(ang, &s, &c);
    tab[i] = make_float2(c, s);
    return;
  }
  int i = bid * 256 + threadIdx.x;                  // 2,097,152 units of 4 floats
  const float4* src; u16* dst;
  if (i < 1048576) {                                // x
    src = x + i; dst = xb + (size_t)i * 4;
  } else if (i < 1835008) {                         // Wq,Wk,Wv
    int j = i - 1048576;
    int w = j >> 18;
    int e = j & 262143;
    src = (w == 0 ? wq : (w == 1 ? wk : wv)) + e;
    dst = wqkvb + (size_t)w * 1048576 + (size_t)e * 4;
  } else {                                          // Wo
    int j = i - 1835008;
    src = wo + j; dst = wob + (size_t)j * 4;
  }
  float4 v = *src;
  u32 lo = (u32)f2bf(v.x) | ((u32)f2bf(v.y) << 16);
  u32 hi = (u32)f2bf(v.z) | ((u32)f2bf(v.w) << 16);
  u32* d32 = (u32*)dst;
  d32[0] = lo; d32[1] = hi;
}

// ------- fused prep: RoPE apply on Q,K columns  +  V transpose (disjoint data) --
__global__ __launch_bounds__(256) void prep_kernel(
    u16* __restrict__ qkv, const int* __restrict__ tpos, const float2* __restrict__ tab,
    u16* __restrict__ vt)
{
  int bid = blockIdx.x;
  if (bid < 16384) {
    int tid = bid * 256 + threadIdx.x;              // 4096 rows * 1024 pairs
    int m    = tid >> 10;
    int pp   = tid & 1023;
    int slot = pp >> 5;
    int p    = pp & 31;
    int col  = slot * 64 + 2 * p;
    u32* addr = (u32*)(qkv + (size_t)m * NQKV + col);
    u32 v = *addr;
    float x1 = bf2f((u16)(v & 0xffff));
    float x2 = bf2f((u16)(v >> 16));
    int pos = tpos[m];
    float2 cs = tab[(size_t)pos * 32 + p];
    float r1 = x1 * cs.x - x2 * cs.y;
    float r2 = x1 * cs.y + x2 * cs.x;
    *addr = (u32)f2bf(r1) | ((u32)f2bf(r2) << 16);
  } else {
    int idx  = bid - 16384;                         // 0..2047
    int kblk = idx & 7;
    int d0   = (idx >> 3) & 7;
    int bh   = idx >> 6;
    int b = bh >> 4, h = bh & 15;
    int k = kblk * 256 + threadIdx.x;
    const u16* src = qkv + (size_t)(b * SEQ + k) * NQKV + 2 * D_MODEL + h * HD + d0 * 8;
    short8 v = *(const short8*)src;
    u16* dst = vt + ((size_t)bh * HD + d0 * 8) * VTS + k;
    #pragma unroll
    for (int j = 0; j < 8; ++j) dst[(size_t)j * VTS] = (u16)v[j];
  }
}

// ---------------- bf16 GEMM, C[m][n] = sum_k A[m][k]*B[n][k]  (B^T layout) ------
// 128x128 tile, 3-slot ring, single barrier (R16-proven), XCD swizzle (T1).
template<typename OutT>
__global__ __launch_bounds__(256) void gemm_bt(
    const u16* __restrict__ A, const u16* __restrict__ B, OutT* __restrict__ C,
    int M, int N, int K, int NBX)
{
  __shared__ __align__(16) u16 As[3][128 * 32];   // 24 KB
  __shared__ __align__(16) u16 Bs[3][128 * 32];   // 24 KB
  int lin = blockIdx.x;
  int per = (int)gridDim.x >> 3;
  int swz = (lin & 7) * per + (lin >> 3);          // bijective (gridDim.x % 8 == 0)
  int bx = swz % NBX, by = swz / NBX;
  int t = threadIdx.x;
  int w = t >> 6, l = t & 63, g = l >> 4, c = l & 15;
  int wr = w >> 1, wc = w & 1;
  int bm = by * 128, bn = bx * 128;

  const u16* aS0 = A + (size_t)(bm + (t >> 2)) * K + (t & 3) * 8;
  const u16* aS1 = aS0 + (size_t)64 * K;
  const u16* bS0 = B + (size_t)(bn + (t >> 2)) * K + (t & 3) * 8;
  const u16* bS1 = bS0 + (size_t)64 * K;

  auto STAGE = [&](int step) {
    int slot = step % 3;
    int kk = step * 32;
    gload16(aS0 + kk, (char*)&As[slot][0] + w * 1024);
    gload16(aS1 + kk, (char*)&As[slot][0] + 4096 + w * 1024);
    gload16(bS0 + kk, (char*)&Bs[slot][0] + w * 1024);
    gload16(bS1 + kk, (char*)&Bs[slot][0] + 4096 + w * 1024);
  };

  f32x4 z = {0.f, 0.f, 0.f, 0.f};
  f32x4 acc[4][4];
  #pragma unroll
  for (int i = 0; i < 4; i++)
    #pragma unroll
    for (int j = 0; j < 4; j++) acc[i][j] = z;

  int nk = K >> 5;
  STAGE(0);
  if (nk > 1) STAGE(1);

  for (int step = 0; step < nk; ++step) {
    if (step + 1 < nk) {
      asm volatile("s_waitcnt vmcnt(4)" ::: "memory");   // only next tile's 4 in flight
    } else {
      asm volatile("s_waitcnt vmcnt(0)" ::: "memory");
    }
    __syncthreads();
    if (step + 2 < nk) STAGE(step + 2);                  // overwrites slot (step-1)%3: safe

    int slot = step % 3;
    const u16* Ac = &As[slot][0];
    const u16* Bc = &Bs[slot][0];
    short8 af[4], bfr[4];
    #pragma unroll
    for (int i = 0; i < 4; i++)
      af[i] = *(const short8*)&Ac[(size_t)(wr * 64 + i * 16 + c) * 32 + g * 8];
    #pragma unroll
    for (int j = 0; j < 4; j++)
      bfr[j] = *(const short8*)&Bc[(size_t)(wc * 64 + j * 16 + c) * 32 + g * 8];
    #pragma unroll
    for (int i = 0; i < 4; i++)
      #pragma unroll
      for (int j = 0; j < 4; j++)
        acc[i][j] = __builtin_amdgcn_mfma_f32_16x16x32_bf16(af[i], bfr[j], acc[i][j], 0, 0, 0);
  }

  #pragma unroll
  for (int i = 0; i < 4; i++) {
    int row0 = bm + wr * 64 + i * 16 + 4 * g;
    #pragma unroll
    for (int j = 0; j < 4; j++) {
      int col = bn + wc * 64 + j * 16 + c;
      #pragma unroll
      for (int r = 0; r < 4; r++) {
        float v = acc[i][j][r];
        size_t idx = (size_t)(row0 + r) * N + col;
        if constexpr (sizeof(OutT) == 2) ((u16*)C)[idx] = f2bf(v);
        else                             ((float*)C)[idx] = v;
      }
    }
  }
}

// ---------------- bf16 GEMM 64x64 tile: 4 waves (2x2 of 32x32), ring schedule ---
// For gemm2 (N=1024): 1024 blocks = 4/CU (vs 2/CU at 128x64) — same total
// A/B traffic, double the residency. STAGE = 2 loads -> vmcnt(2)/0.
__global__ __launch_bounds__(256) void gemm_bt_64(
    const u16* __restrict__ A, const u16* __restrict__ B, float* __restrict__ C,
    int M, int N, int K, int NBX)
{
  __shared__ __align__(16) u16 As[3][64 * 32];    // 12 KB
  __shared__ __align__(16) u16 Bs[3][64 * 32];    // 12 KB
  int lin = blockIdx.x;
  int per = (int)gridDim.x >> 3;
  int swz = (lin & 7) * per + (lin >> 3);
  int bx = swz % NBX, by = swz / NBX;
  int t = threadIdx.x;
  int w = t >> 6, l = t & 63, g = l >> 4, c = l & 15;
  int wr = w >> 1, wc = w & 1;
  int bm = by * 64, bn = bx * 64;

  const u16* aS0 = A + (size_t)(bm + (t >> 2)) * K + (t & 3) * 8;
  const u16* bS0 = B + (size_t)(bn + (t >> 2)) * K + (t & 3) * 8;

  auto STAGE = [&](int step) {
    int slot = step % 3;
    int kk = step * 32;
    gload16(aS0 + kk, (char*)&As[slot][0] + t * 16);
    gload16(bS0 + kk, (char*)&Bs[slot][0] + t * 16);
  };

  f32x4 z = {0.f, 0.f, 0.f, 0.f};
  f32x4 acc[2][2];
  #pragma unroll
  for (int i = 0; i < 2; i++) { acc[i][0] = z; acc[i][1] = z; }

  int nk = K >> 5;
  STAGE(0);
  if (nk > 1) STAGE(1);

  for (int step = 0; step < nk; ++step) {
    if (step + 1 < nk) {
      asm volatile("s_waitcnt vmcnt(2)" ::: "memory");   // only next tile's 2 in flight
    } else {
      asm volatile("s_waitcnt vmcnt(0)" ::: "memory");
    }
    __syncthreads();
    if (step + 2 < nk) STAGE(step + 2);

    int slot = step % 3;
    const u16* Ac = &As[slot][0];
    const u16* Bc = &Bs[slot][0];
    short8 af[2], bfr[2];
    #pragma unroll
    for (int i = 0; i < 2; i++)
      af[i] = *(const short8*)&Ac[(size_t)(wr * 32 + i * 16 + c) * 32 + g * 8];
    #pragma unroll
    for (int j = 0; j < 2; j++)
      bfr[j] = *(const short8*)&Bc[(size_t)(wc * 32 + j * 16 + c) * 32 + g * 8];
    #pragma unroll
    for (int i = 0; i < 2; i++)
      #pragma unroll
      for (int j = 0; j < 2; j++)
        acc[i][j] = __builtin_amdgcn_mfma_f32_16x16x32_bf16(af[i], bfr[j], acc[i][j], 0, 0, 0);
  }

  #pragma unroll
  for (int i = 0; i < 2; i++) {
    int row0 = bm + wr * 32 + i * 16 + 4 * g;
    #pragma unroll
    for (int j = 0; j < 2; j++) {
      int col = bn + wc * 32 + j * 16 + c;
      #pragma unroll
      for (int r = 0; r < 4; r++)
        C[(size_t)(row0 + r) * N + col] = acc[i][j][r];
    }
  }
}

// ---------------- causal flash attention (R16-exact: best measured config) ------
// 1 q-block/block (1024 blocks, heavy-first), bh->XCD affinity, 3-slot ring,
// 2-deep prefetch, single barrier per tile, counted vmcnt 4/0, exp2 softmax,
// exact skip-rescale, packed RNE converts.
#define STAGE_TILE(ktile)                                                       \
  {                                                                             \
    int _slot = (ktile) % 3;                                                    \
    int _k0 = (ktile) << 6;                                                     \
    _Pragma("unroll")                                                           \
    for (int _i = 0; _i < 2; ++_i) {                                            \
      int _row = w * 16 + _i * 8 + srow8;                                       \
      gload16(Kb + (size_t)(_k0 + _row) * NQKV + swzc,                          \
              (char*)&Ks[_slot][0] + w * 2048 + _i * 1024);                     \
      gload16(Vtb + (size_t)_row * VTS + _k0 + swzc,                            \
              (char*)&Vs[_slot][0] + w * 2048 + _i * 1024);                     \
    }                                                                           \
  }

__global__ __launch_bounds__(256) void attn_kernel(
    const u16* __restrict__ qkv, const u16* __restrict__ vt, u16* __restrict__ ctx)
{
  __shared__ __align__(16) u16 Ks[3][64 * 64];   // 24 KB
  __shared__ __align__(16) u16 Vs[3][64 * 64];   // 24 KB
  const float C1 = 0.18033688011112042f;         // 0.125 * log2(e)
  int lin  = blockIdx.x;                         // 0..1023
  int bh   = lin & 31;                           // stable bh->XCD affinity
  int qblk = 31 - (lin >> 5);                    // heavy blocks dispatch first
  int b = bh >> 4, h = bh & 15;
  int t = threadIdx.x;
  int w = t >> 6, l = t & 63, g = l >> 4, c = l & 15;
  const u16* base = qkv + (size_t)b * SEQ * NQKV;
  const u16* Qb = base + h * HD;
  const u16* Kb = base + D_MODEL + h * HD;
  const u16* Vtb = vt + (size_t)bh * HD * VTS;   // [d][k], row stride VTS

  int srow8 = l >> 3;                 // 0..7 row within issue
  int swzc  = ((l & 7) ^ srow8) << 3; // inverse-swizzled chunk -> elem offset

  f32x4 z = {0.f, 0.f, 0.f, 0.f};
  int q0 = qblk * 64 + w * 16;
  int q = q0 + c;
  short8 qf0 = *(const short8*)(Qb + (size_t)q * NQKV + g * 8);
  short8 qf1 = *(const short8*)(Qb + (size_t)q * NQKV + 32 + g * 8);

  f32x4 o[4] = {z, z, z, z};
  float mrun = -1e30f, lrun = 0.f;

  // ---- prologue: stage tiles 0 (and 1) ----
  STAGE_TILE(0);
  if (qblk >= 1) STAGE_TILE(1);

  for (int kt = 0; kt <= qblk; ++kt) {
    int k0 = kt << 6;
    if (kt + 1 <= qblk) {
      asm volatile("s_waitcnt vmcnt(4)" ::: "memory");   // only tile kt+1's 4 in flight
    } else {
      asm volatile("s_waitcnt vmcnt(0)" ::: "memory");
    }
    __syncthreads();
    if (kt + 2 <= qblk) STAGE_TILE(kt + 2);              // overwrites slot (kt-1)%3: safe

    int slot = kt % 3;
    const u16* Kc = &Ks[slot][0];
    const u16* Vc = &Vs[slot][0];

    // ---- QK^T: S^T[k][q] (raw scores), 4 sub-tiles of 16 keys ----
    f32x4 s[4] = {z, z, z, z};
    #pragma unroll
    for (int sub = 0; sub < 4; ++sub) {
      const u16* kr = Kc + (sub * 16 + c) * 64;
      short8 kf0 = *(const short8*)(kr + ((g       ^ (c & 7)) << 3));
      short8 kf1 = *(const short8*)(kr + (((4 + g) ^ (c & 7)) << 3));
      s[sub] = __builtin_amdgcn_mfma_f32_16x16x32_bf16(kf0, qf0, s[sub], 0, 0, 0);
      s[sub] = __builtin_amdgcn_mfma_f32_16x16x32_bf16(kf1, qf1, s[sub], 0, 0, 0);
    }

    // ---- causal mask (raw domain, only last tile) ----
    float sc[4][4];
    if (kt == qblk) {
      #pragma unroll
      for (int sub = 0; sub < 4; ++sub)
        #pragma unroll
        for (int r = 0; r < 4; ++r) {
          int k = k0 + sub * 16 + 4 * g + r;
          sc[sub][r] = (k <= q) ? s[sub][r] : -1e30f;
        }
    } else {
      #pragma unroll
      for (int sub = 0; sub < 4; ++sub)
        #pragma unroll
        for (int r = 0; r < 4; ++r)
          sc[sub][r] = s[sub][r];
    }

    // ---- online softmax (raw max; exp2 folded scale; exact skip-rescale) ----
    float tm = fmaxf(fmaxf(fmaxf(sc[0][0], sc[0][1]), fmaxf(sc[0][2], sc[0][3])),
                     fmaxf(fmaxf(sc[1][0], sc[1][1]), fmaxf(sc[1][2], sc[1][3])));
    float tm2 = fmaxf(fmaxf(fmaxf(sc[2][0], sc[2][1]), fmaxf(sc[2][2], sc[2][3])),
                      fmaxf(fmaxf(sc[3][0], sc[3][1]), fmaxf(sc[3][2], sc[3][3])));
    tm = fmaxf(tm, tm2);
    tm = fmaxf(tm, __shfl_xor(tm, 16));
    tm = fmaxf(tm, __shfl_xor(tm, 32));
    // If no lane's max grew, alpha == 1 exactly -> rescale is the identity.
    if (!__all(tm <= mrun)) {
      float mnew = fmaxf(mrun, tm);
      float alpha = __builtin_amdgcn_exp2f((mrun - mnew) * C1);
      lrun *= alpha;
      #pragma unroll
      for (int dt = 0; dt < 4; ++dt) {
        o[dt][0] *= alpha; o[dt][1] *= alpha; o[dt][2] *= alpha; o[dt][3] *= alpha;
      }
      mrun = mnew;
    }
    float nb = -mrun * C1;
    float rs = 0.f;
    #pragma unroll
    for (int sub = 0; sub < 4; ++sub) {
      #pragma unroll
      for (int r = 0; r < 4; ++r) {
        sc[sub][r] = __builtin_amdgcn_exp2f(fmaf(sc[sub][r], C1, nb));
        rs += sc[sub][r];
      }
    }
    rs += __shfl_xor(rs, 16);
    rs += __shfl_xor(rs, 32);
    lrun += rs;

    // ---- P -> bf16 fragments (packed RNE convert, R14-proven) ----
    short4v pf[4];
    #pragma unroll
    for (int sub = 0; sub < 4; ++sub)
      pf[sub] = pack4(sc[sub][0], sc[sub][1], sc[sub][2], sc[sub][3]);

    // ---- PV: O^T[d][q] += V^T[d][k] * P^T[k][q], swizzled b64 LDS reads ----
    #pragma unroll
    for (int sub = 0; sub < 4; ++sub) {
      #pragma unroll
      for (int dt = 0; dt < 4; ++dt) {
        int ch = sub * 2 + (g >> 1);
        const u16* vp = Vc + (dt * 16 + c) * 64 + ((ch ^ (c & 7)) << 3) + ((g & 1) << 2);
        short4v vf = *(const short4v*)vp;
        o[dt] = __builtin_amdgcn_mfma_f32_16x16x16bf16_1k(vf, pf[sub], o[dt], 0, 0, 0);
      }
    }
    // no trailing barrier: next iter's pre-compute barrier orders slot reuse
  }

  float inv = 1.0f / lrun;
  size_t obase = ((size_t)b * SEQ + q) * D_MODEL + h * HD;
  #pragma unroll
  for (int dt = 0; dt < 4; ++dt) {
    u32 lo = pkbf(o[dt][0] * inv, o[dt][1] * inv);
    u32 hi = pkbf(o[dt][2] * inv, o[dt][3] * inv);
    u32* dp = (u32*)(ctx + obase + dt * 16 + 4 * g);
    dp[0] = lo; dp[1] = hi;
  }
}

// ---------------- launch ----------------
extern "C" void kernel_launch(void* const* d_in, const int* in_sizes, int n_in,
                              void* d_out, int out_size, void* d_ws, size_t ws_size,
                              hipStream_t stream)
{
  const float* x   = (const float*)d_in[0];
  const int*  tpos = (const int*) d_in[1];
  const float* Wq  = (const float*)d_in[2];
  const float* Wk  = (const float*)d_in[3];
  const float* Wv  = (const float*)d_in[4];
  const float* Wo  = (const float*)d_in[5];

  char* ws = (char*)d_ws;
  u16*    xb    = (u16*)(ws);                   //  8,388,608 B (dead after gemm1)
  u16*    vt    = (u16*)(ws);                   //  8,421,376 B V^T (clobbers dead xb)
  u16*    wqkvb = (u16*)(ws + 8388608);         //  6,291,456 B (dead after gemm1)
  u16*    wob   = (u16*)(ws + 14680064);        //  2,097,152 B
  u16*    qkvb  = (u16*)(ws + 16777216);        // 25,165,824 B
  u16*    ctx   = (u16*)(ws + 41943040);        //  8,388,608 B
  float2* tab   = (float2*)(ws + 50331648);     //    524,288 B

  convert_kernel<<<8448, 256, 0, stream>>>(
      (const float4*)x, (const float4*)Wq, (const float4*)Wk, (const float4*)Wv, (const float4*)Wo,
      xb, wqkvb, wob, tab);
  gemm_bt<u16><<<(NQKV / 128) * (MTOT / 128), 256, 0, stream>>>(
      xb, wqkvb, qkvb, MTOT, NQKV, D_MODEL, NQKV / 128);
  prep_kernel<<<18432, 256, 0, stream>>>(qkvb, tpos, tab, vt);
  attn_kernel<<<1024, 256, 0, stream>>>(qkvb, vt, ctx);
  gemm_bt_64<<<(D_MODEL / 64) * (MTOT / 64), 256, 0, stream>>>(
      ctx, wob, (float*)d_out, MTOT, D_MODEL, D_MODEL, D_MODEL / 64);
}

// Round 20
// 120.016 us; speedup vs baseline: 1.0908x; 1.0477x over previous
//
#include <hip/hip_runtime.h>
#include <hip/hip_bf16.h>
#include <cstdint>
#include <cstddef>

typedef unsigned short u16;
typedef unsigned int   u32;
typedef __attribute__((ext_vector_type(8))) short short8;
typedef __attribute__((ext_vector_type(4))) short short4v;
typedef __attribute__((ext_vector_type(4))) unsigned int u32x4;
typedef __attribute__((ext_vector_type(4))) float f32x4;

#define D_MODEL 1024
#define NH      16
#define HD      64
#define SEQ     2048
#define BATCH   2
#define MTOT    (BATCH*SEQ)   // 4096
#define NQKV    3072
#define VTS     2056          // padded V^T row stride (elems)

__device__ __forceinline__ float bf2f(u16 h){ u32 u = ((u32)h) << 16; float f; __builtin_memcpy(&f, &u, 4); return f; }
__device__ __forceinline__ u16 f2bf(float f){ u32 u; __builtin_memcpy(&u, &f, 4); u = (u + 0x7FFFu + ((u >> 16) & 1u)) >> 16; return (u16)u; }

// packed fp32->bf16 via the official HIP intrinsic (RNE; R14-proven).
__device__ __forceinline__ u32 pkbf(float a, float b){
  __hip_bfloat162 h = __float22bfloat162_rn(make_float2(a, b));
  u32 r; __builtin_memcpy(&r, &h, 4); return r;
}
__device__ __forceinline__ short4v pack4(float a, float b, float c, float d){
  u32 lo = pkbf(a, b), hi = pkbf(c, d);
  short4v r;
  __builtin_memcpy(&r, &lo, 4);
  __builtin_memcpy(((char*)&r) + 4, &hi, 4);
  return r;
}

__device__ __forceinline__ void gload16(const void* g, void* s){
  __builtin_amdgcn_global_load_lds((const __attribute__((address_space(1))) void*)g,
                                   (__attribute__((address_space(3))) void*)s, 16, 0, 0);
}

// ------- convert fp32 -> bf16 (x, Wq|Wk|Wv packed, Wo) + RoPE table (fused) -----
__global__ __launch_bounds__(256) void convert_kernel(
    const float4* __restrict__ x, const float4* __restrict__ wq, const float4* __restrict__ wk,
    const float4* __restrict__ wv, const float4* __restrict__ wo,
    u16* __restrict__ xb, u16* __restrict__ wqkvb, u16* __restrict__ wob,
    float2* __restrict__ tab)
{
  int bid = blockIdx.x;
  if (bid >= 8192) {                                // RoPE cos/sin table part
    int i = (bid - 8192) * 256 + threadIdx.x;       // 65536 = 2048 pos * 32 pairs
    int pos = i >> 5, p = i & 31;
    float freq = __expf(-(float)p * (9.210340371976184f / 32.0f));
    float ang = (float)pos * freq;
    float s, c;
    sincosf(ang, &s, &c);
    tab[i] = make_float2(c, s);
    return;
  }
  int i = bid * 256 + threadIdx.x;                  // 2,097,152 units of 4 floats
  const float4* src; u16* dst;
  if (i < 1048576) {                                // x
    src = x + i; dst = xb + (size_t)i * 4;
  } else if (i < 1835008) {                         // Wq,Wk,Wv
    int j = i - 1048576;
    int w = j >> 18;
    int e = j & 262143;
    src = (w == 0 ? wq : (w == 1 ? wk : wv)) + e;
    dst = wqkvb + (size_t)w * 1048576 + (size_t)e * 4;
  } else {                                          // Wo
    int j = i - 1835008;
    src = wo + j; dst = wob + (size_t)j * 4;
  }
  float4 v = *src;
  u32 lo = (u32)f2bf(v.x) | ((u32)f2bf(v.y) << 16);
  u32 hi = (u32)f2bf(v.z) | ((u32)f2bf(v.w) << 16);
  u32* d32 = (u32*)dst;
  d32[0] = lo; d32[1] = hi;
}

// ------- fused prep: RoPE apply (vectorized, 4 pairs/thread) + V transpose ------
__global__ __launch_bounds__(256) void prep_kernel(
    u16* __restrict__ qkv, const int* __restrict__ tpos, const float2* __restrict__ tab,
    u16* __restrict__ vt)
{
  int bid = blockIdx.x;
  if (bid < 4096) {
    // ---- RoPE apply in-place: 4 consecutive pairs (16B) per thread ----
    int tid  = bid * 256 + threadIdx.x;             // 1,048,576 = 4096 rows * 256 quads
    int m    = tid >> 8;
    int r    = tid & 255;
    int slot = r >> 3;                              // 0..31 (16 Q heads, 16 K heads)
    int p4   = r & 7;                               // quad index: pairs 4*p4..4*p4+3
    int col  = slot * 64 + 8 * p4;
    u32* addr = (u32*)(qkv + (size_t)m * NQKV + col);
    u32x4 v = *(const u32x4*)addr;
    int pos = tpos[m];
    const float2* tb = tab + (size_t)pos * 32 + 4 * p4;
    u32x4 out;
    #pragma unroll
    for (int j = 0; j < 4; ++j) {
      float x1 = bf2f((u16)(v[j] & 0xffff));
      float x2 = bf2f((u16)(v[j] >> 16));
      float2 cs = tb[j];
      float r1 = x1 * cs.x - x2 * cs.y;
      float r2 = x1 * cs.y + x2 * cs.x;
      out[j] = (u32)f2bf(r1) | ((u32)f2bf(r2) << 16);
    }
    *(u32x4*)addr = out;
  } else {
    // ---- V transpose: vt[bh][d][k] (row stride VTS), V columns untouched ----
    int idx  = bid - 4096;                          // 0..2047
    int kblk = idx & 7;
    int d0   = (idx >> 3) & 7;
    int bh   = idx >> 6;
    int b = bh >> 4, h = bh & 15;
    int k = kblk * 256 + threadIdx.x;
    const u16* src = qkv + (size_t)(b * SEQ + k) * NQKV + 2 * D_MODEL + h * HD + d0 * 8;
    short8 v = *(const short8*)src;
    u16* dst = vt + ((size_t)bh * HD + d0 * 8) * VTS + k;
    #pragma unroll
    for (int j = 0; j < 8; ++j) dst[(size_t)j * VTS] = (u16)v[j];
  }
}

// ---------------- bf16 GEMM, C[m][n] = sum_k A[m][k]*B[n][k]  (B^T layout) ------
// 128x128 tile, 3-slot ring, single barrier (R16-proven). R19: 2-D grouped XCD
// swizzle — each XCD gets an 8(by) x 12(bx) super-tile (L2 footprint 2MB A +
// 3MB B = 5MB, vs 7MB with the row-major split). Pure bijective relabel.
template<typename OutT>
__global__ __launch_bounds__(256) void gemm_bt(
    const u16* __restrict__ A, const u16* __restrict__ B, OutT* __restrict__ C,
    int M, int N, int K, int NBX)
{
  __shared__ __align__(16) u16 As[3][128 * 32];   // 24 KB
  __shared__ __align__(16) u16 Bs[3][128 * 32];   // 24 KB
  int lin = blockIdx.x;
  int xcd = lin & 7;
  int idx = lin >> 3;                              // 0..95 within XCD
  int byl = idx / 12, bxl = idx % 12;              // 8 x 12 local grid
  int by  = ((xcd >> 1) << 3) + byl;               // 4 row-octs (32 by total)
  int bx  = ((xcd & 1) * 12) + bxl;                // 2 col-halves (24 bx total)
  int t = threadIdx.x;
  int w = t >> 6, l = t & 63, g = l >> 4, c = l & 15;
  int wr = w >> 1, wc = w & 1;
  int bm = by * 128, bn = bx * 128;

  const u16* aS0 = A + (size_t)(bm + (t >> 2)) * K + (t & 3) * 8;
  const u16* aS1 = aS0 + (size_t)64 * K;
  const u16* bS0 = B + (size_t)(bn + (t >> 2)) * K + (t & 3) * 8;
  const u16* bS1 = bS0 + (size_t)64 * K;

  auto STAGE = [&](int step) {
    int slot = step % 3;
    int kk = step * 32;
    gload16(aS0 + kk, (char*)&As[slot][0] + w * 1024);
    gload16(aS1 + kk, (char*)&As[slot][0] + 4096 + w * 1024);
    gload16(bS0 + kk, (char*)&Bs[slot][0] + w * 1024);
    gload16(bS1 + kk, (char*)&Bs[slot][0] + 4096 + w * 1024);
  };

  f32x4 z = {0.f, 0.f, 0.f, 0.f};
  f32x4 acc[4][4];
  #pragma unroll
  for (int i = 0; i < 4; i++)
    #pragma unroll
    for (int j = 0; j < 4; j++) acc[i][j] = z;

  int nk = K >> 5;
  STAGE(0);
  if (nk > 1) STAGE(1);

  for (int step = 0; step < nk; ++step) {
    if (step + 1 < nk) {
      asm volatile("s_waitcnt vmcnt(4)" ::: "memory");   // only next tile's 4 in flight
    } else {
      asm volatile("s_waitcnt vmcnt(0)" ::: "memory");
    }
    __syncthreads();
    if (step + 2 < nk) STAGE(step + 2);                  // overwrites slot (step-1)%3: safe

    int slot = step % 3;
    const u16* Ac = &As[slot][0];
    const u16* Bc = &Bs[slot][0];
    short8 af[4], bfr[4];
    #pragma unroll
    for (int i = 0; i < 4; i++)
      af[i] = *(const short8*)&Ac[(size_t)(wr * 64 + i * 16 + c) * 32 + g * 8];
    #pragma unroll
    for (int j = 0; j < 4; j++)
      bfr[j] = *(const short8*)&Bc[(size_t)(wc * 64 + j * 16 + c) * 32 + g * 8];
    #pragma unroll
    for (int i = 0; i < 4; i++)
      #pragma unroll
      for (int j = 0; j < 4; j++)
        acc[i][j] = __builtin_amdgcn_mfma_f32_16x16x32_bf16(af[i], bfr[j], acc[i][j], 0, 0, 0);
  }

  #pragma unroll
  for (int i = 0; i < 4; i++) {
    int row0 = bm + wr * 64 + i * 16 + 4 * g;
    #pragma unroll
    for (int j = 0; j < 4; j++) {
      int col = bn + wc * 64 + j * 16 + c;
      #pragma unroll
      for (int r = 0; r < 4; r++) {
        float v = acc[i][j][r];
        size_t idx2 = (size_t)(row0 + r) * N + col;
        if constexpr (sizeof(OutT) == 2) ((u16*)C)[idx2] = f2bf(v);
        else                             ((float*)C)[idx2] = v;
      }
    }
  }
}

// ---------------- bf16 GEMM 64x64 tile: 4 waves (2x2 of 32x32), ring schedule ---
__global__ __launch_bounds__(256) void gemm_bt_64(
    const u16* __restrict__ A, const u16* __restrict__ B, float* __restrict__ C,
    int M, int N, int K, int NBX)
{
  __shared__ __align__(16) u16 As[3][64 * 32];    // 12 KB
  __shared__ __align__(16) u16 Bs[3][64 * 32];    // 12 KB
  int lin = blockIdx.x;
  int per = (int)gridDim.x >> 3;
  int swz = (lin & 7) * per + (lin >> 3);
  int bx = swz % NBX, by = swz / NBX;
  int t = threadIdx.x;
  int w = t >> 6, l = t & 63, g = l >> 4, c = l & 15;
  int wr = w >> 1, wc = w & 1;
  int bm = by * 64, bn = bx * 64;

  const u16* aS0 = A + (size_t)(bm + (t >> 2)) * K + (t & 3) * 8;
  const u16* bS0 = B + (size_t)(bn + (t >> 2)) * K + (t & 3) * 8;

  auto STAGE = [&](int step) {
    int slot = step % 3;
    int kk = step * 32;
    gload16(aS0 + kk, (char*)&As[slot][0] + t * 16);
    gload16(bS0 + kk, (char*)&Bs[slot][0] + t * 16);
  };

  f32x4 z = {0.f, 0.f, 0.f, 0.f};
  f32x4 acc[2][2];
  #pragma unroll
  for (int i = 0; i < 2; i++) { acc[i][0] = z; acc[i][1] = z; }

  int nk = K >> 5;
  STAGE(0);
  if (nk > 1) STAGE(1);

  for (int step = 0; step < nk; ++step) {
    if (step + 1 < nk) {
      asm volatile("s_waitcnt vmcnt(2)" ::: "memory");
    } else {
      asm volatile("s_waitcnt vmcnt(0)" ::: "memory");
    }
    __syncthreads();
    if (step + 2 < nk) STAGE(step + 2);

    int slot = step % 3;
    const u16* Ac = &As[slot][0];
    const u16* Bc = &Bs[slot][0];
    short8 af[2], bfr[2];
    #pragma unroll
    for (int i = 0; i < 2; i++)
      af[i] = *(const short8*)&Ac[(size_t)(wr * 32 + i * 16 + c) * 32 + g * 8];
    #pragma unroll
    for (int j = 0; j < 2; j++)
      bfr[j] = *(const short8*)&Bc[(size_t)(wc * 32 + j * 16 + c) * 32 + g * 8];
    #pragma unroll
    for (int i = 0; i < 2; i++)
      #pragma unroll
      for (int j = 0; j < 2; j++)
        acc[i][j] = __builtin_amdgcn_mfma_f32_16x16x32_bf16(af[i], bfr[j], acc[i][j], 0, 0, 0);
  }

  #pragma unroll
  for (int i = 0; i < 2; i++) {
    int row0 = bm + wr * 32 + i * 16 + 4 * g;
    #pragma unroll
    for (int j = 0; j < 2; j++) {
      int col = bn + wc * 32 + j * 16 + c;
      #pragma unroll
      for (int r = 0; r < 4; r++)
        C[(size_t)(row0 + r) * N + col] = acc[i][j][r];
    }
  }
}

// ---------------- causal flash attention (R16-exact: best measured config) ------
#define STAGE_TILE(ktile)                                                       \
  {                                                                             \
    int _slot = (ktile) % 3;                                                    \
    int _k0 = (ktile) << 6;                                                     \
    _Pragma("unroll")                                                           \
    for (int _i = 0; _i < 2; ++_i) {                                            \
      int _row = w * 16 + _i * 8 + srow8;                                       \
      gload16(Kb + (size_t)(_k0 + _row) * NQKV + swzc,                          \
              (char*)&Ks[_slot][0] + w * 2048 + _i * 1024);                     \
      gload16(Vtb + (size_t)_row * VTS + _k0 + swzc,                            \
              (char*)&Vs[_slot][0] + w * 2048 + _i * 1024);                     \
    }                                                                           \
  }

__global__ __launch_bounds__(256) void attn_kernel(
    const u16* __restrict__ qkv, const u16* __restrict__ vt, u16* __restrict__ ctx)
{
  __shared__ __align__(16) u16 Ks[3][64 * 64];   // 24 KB
  __shared__ __align__(16) u16 Vs[3][64 * 64];   // 24 KB
  const float C1 = 0.18033688011112042f;         // 0.125 * log2(e)
  int lin  = blockIdx.x;                         // 0..1023
  int bh   = lin & 31;                           // stable bh->XCD affinity
  int qblk = 31 - (lin >> 5);                    // heavy blocks dispatch first
  int b = bh >> 4, h = bh & 15;
  int t = threadIdx.x;
  int w = t >> 6, l = t & 63, g = l >> 4, c = l & 15;
  const u16* base = qkv + (size_t)b * SEQ * NQKV;
  const u16* Qb = base + h * HD;
  const u16* Kb = base + D_MODEL + h * HD;
  const u16* Vtb = vt + (size_t)bh * HD * VTS;   // [d][k], row stride VTS

  int srow8 = l >> 3;                 // 0..7 row within issue
  int swzc  = ((l & 7) ^ srow8) << 3; // inverse-swizzled chunk -> elem offset

  f32x4 z = {0.f, 0.f, 0.f, 0.f};
  int q0 = qblk * 64 + w * 16;
  int q = q0 + c;
  short8 qf0 = *(const short8*)(Qb + (size_t)q * NQKV + g * 8);
  short8 qf1 = *(const short8*)(Qb + (size_t)q * NQKV + 32 + g * 8);

  f32x4 o[4] = {z, z, z, z};
  float mrun = -1e30f, lrun = 0.f;

  // ---- prologue: stage tiles 0 (and 1) ----
  STAGE_TILE(0);
  if (qblk >= 1) STAGE_TILE(1);

  for (int kt = 0; kt <= qblk; ++kt) {
    int k0 = kt << 6;
    if (kt + 1 <= qblk) {
      asm volatile("s_waitcnt vmcnt(4)" ::: "memory");   // only tile kt+1's 4 in flight
    } else {
      asm volatile("s_waitcnt vmcnt(0)" ::: "memory");
    }
    __syncthreads();
    if (kt + 2 <= qblk) STAGE_TILE(kt + 2);              // overwrites slot (kt-1)%3: safe

    int slot = kt % 3;
    const u16* Kc = &Ks[slot][0];
    const u16* Vc = &Vs[slot][0];

    // ---- QK^T: S^T[k][q] (raw scores), 4 sub-tiles of 16 keys ----
    f32x4 s[4] = {z, z, z, z};
    #pragma unroll
    for (int sub = 0; sub < 4; ++sub) {
      const u16* kr = Kc + (sub * 16 + c) * 64;
      short8 kf0 = *(const short8*)(kr + ((g       ^ (c & 7)) << 3));
      short8 kf1 = *(const short8*)(kr + (((4 + g) ^ (c & 7)) << 3));
      s[sub] = __builtin_amdgcn_mfma_f32_16x16x32_bf16(kf0, qf0, s[sub], 0, 0, 0);
      s[sub] = __builtin_amdgcn_mfma_f32_16x16x32_bf16(kf1, qf1, s[sub], 0, 0, 0);
    }

    // ---- causal mask (raw domain, only last tile) ----
    float sc[4][4];
    if (kt == qblk) {
      #pragma unroll
      for (int sub = 0; sub < 4; ++sub)
        #pragma unroll
        for (int r = 0; r < 4; ++r) {
          int k = k0 + sub * 16 + 4 * g + r;
          sc[sub][r] = (k <= q) ? s[sub][r] : -1e30f;
        }
    } else {
      #pragma unroll
      for (int sub = 0; sub < 4; ++sub)
        #pragma unroll
        for (int r = 0; r < 4; ++r)
          sc[sub][r] = s[sub][r];
    }

    // ---- online softmax (raw max; exp2 folded scale; exact skip-rescale) ----
    float tm = fmaxf(fmaxf(fmaxf(sc[0][0], sc[0][1]), fmaxf(sc[0][2], sc[0][3])),
                     fmaxf(fmaxf(sc[1][0], sc[1][1]), fmaxf(sc[1][2], sc[1][3])));
    float tm2 = fmaxf(fmaxf(fmaxf(sc[2][0], sc[2][1]), fmaxf(sc[2][2], sc[2][3])),
                      fmaxf(fmaxf(sc[3][0], sc[3][1]), fmaxf(sc[3][2], sc[3][3])));
    tm = fmaxf(tm, tm2);
    tm = fmaxf(tm, __shfl_xor(tm, 16));
    tm = fmaxf(tm, __shfl_xor(tm, 32));
    // If no lane's max grew, alpha == 1 exactly -> rescale is the identity.
    if (!__all(tm <= mrun)) {
      float mnew = fmaxf(mrun, tm);
      float alpha = __builtin_amdgcn_exp2f((mrun - mnew) * C1);
      lrun *= alpha;
      #pragma unroll
      for (int dt = 0; dt < 4; ++dt) {
        o[dt][0] *= alpha; o[dt][1] *= alpha; o[dt][2] *= alpha; o[dt][3] *= alpha;
      }
      mrun = mnew;
    }
    float nb = -mrun * C1;
    float rs = 0.f;
    #pragma unroll
    for (int sub = 0; sub < 4; ++sub) {
      #pragma unroll
      for (int r = 0; r < 4; ++r) {
        sc[sub][r] = __builtin_amdgcn_exp2f(fmaf(sc[sub][r], C1, nb));
        rs += sc[sub][r];
      }
    }
    rs += __shfl_xor(rs, 16);
    rs += __shfl_xor(rs, 32);
    lrun += rs;

    // ---- P -> bf16 fragments (packed RNE convert, R14-proven) ----
    short4v pf[4];
    #pragma unroll
    for (int sub = 0; sub < 4; ++sub)
      pf[sub] = pack4(sc[sub][0], sc[sub][1], sc[sub][2], sc[sub][3]);

    // ---- PV: O^T[d][q] += V^T[d][k] * P^T[k][q], swizzled b64 LDS reads ----
    #pragma unroll
    for (int sub = 0; sub < 4; ++sub) {
      #pragma unroll
      for (int dt = 0; dt < 4; ++dt) {
        int ch = sub * 2 + (g >> 1);
        const u16* vp = Vc + (dt * 16 + c) * 64 + ((ch ^ (c & 7)) << 3) + ((g & 1) << 2);
        short4v vf = *(const short4v*)vp;
        o[dt] = __builtin_amdgcn_mfma_f32_16x16x16bf16_1k(vf, pf[sub], o[dt], 0, 0, 0);
      }
    }
    // no trailing barrier: next iter's pre-compute barrier orders slot reuse
  }

  float inv = 1.0f / lrun;
  size_t obase = ((size_t)b * SEQ + q) * D_MODEL + h * HD;
  #pragma unroll
  for (int dt = 0; dt < 4; ++dt) {
    u32 lo = pkbf(o[dt][0] * inv, o[dt][1] * inv);
    u32 hi = pkbf(o[dt][2] * inv, o[dt][3] * inv);
    u32* dp = (u32*)(ctx + obase + dt * 16 + 4 * g);
    dp[0] = lo; dp[1] = hi;
  }
}

// ---------------- launch ----------------
extern "C" void kernel_launch(void* const* d_in, const int* in_sizes, int n_in,
                              void* d_out, int out_size, void* d_ws, size_t ws_size,
                              hipStream_t stream)
{
  const float* x   = (const float*)d_in[0];
  const int*  tpos = (const int*) d_in[1];
  const float* Wq  = (const float*)d_in[2];
  const float* Wk  = (const float*)d_in[3];
  const float* Wv  = (const float*)d_in[4];
  const float* Wo  = (const float*)d_in[5];

  char* ws = (char*)d_ws;
  u16*    xb    = (u16*)(ws);                   //  8,388,608 B (dead after gemm1)
  u16*    vt    = (u16*)(ws);                   //  8,421,376 B V^T (clobbers dead xb)
  u16*    wqkvb = (u16*)(ws + 8388608);         //  6,291,456 B (dead after gemm1)
  u16*    wob   = (u16*)(ws + 14680064);        //  2,097,152 B
  u16*    qkvb  = (u16*)(ws + 16777216);        // 25,165,824 B
  u16*    ctx   = (u16*)(ws + 41943040);        //  8,388,608 B
  float2* tab   = (float2*)(ws + 50331648);     //    524,288 B

  convert_kernel<<<8448, 256, 0, stream>>>(
      (const float4*)x, (const float4*)Wq, (const float4*)Wk, (const float4*)Wv, (const float4*)Wo,
      xb, wqkvb, wob, tab);
  gemm_bt<u16><<<(NQKV / 128) * (MTOT / 128), 256, 0, stream>>>(
      xb, wqkvb, qkvb, MTOT, NQKV, D_MODEL, NQKV / 128);
  prep_kernel<<<6144, 256, 0, stream>>>(qkvb, tpos, tab, vt);
  attn_kernel<<<1024, 256, 0, stream>>>(qkvb, vt, ctx);
  gemm_bt_64<<<(D_MODEL / 64) * (MTOT / 64), 256, 0, stream>>>(
      ctx, wob, (float*)d_out, MTOT, D_MODEL, D_MODEL, D_MODEL / 64);
}